// Round 5
// baseline (139.482 us; speedup 1.0000x reference)
//
#include <hip/hip_runtime.h>

// Problem constants (fixed by reference setup_inputs)
constexpr int Cc   = 3;
constexpr int Hc   = 160;
constexpr int Wc   = 160;
constexpr int Hoc  = 158;
constexpr int Woc  = 158;
constexpr int Lc   = Hoc * Woc;    // 24964
constexpr int Ntot = 4 * Lc;       // 99856
constexpr int NCH  = 8;
constexpr int MDd  = 54;           // 2 * C * 3 * 3

// Bijective (involutive) map float-bits <-> uint such that ascending uint
// == DESCENDING float. Applying it twice recovers the original bits.
__device__ __forceinline__ unsigned inv_key_bits(unsigned u) {
    return (u & 0x80000000u) ? u : (~u & 0x7FFFFFFFu);
}
__device__ __forceinline__ unsigned inv_key(float f) {
    return inv_key_bits(__float_as_uint(f));
}

// amdgpu_waves_per_eu(2,2): cap the allocator's occupancy TARGET at 2
// waves/EU -> register budget 512/2 = 256 regs/wave. Rounds 2-4 showed the
// allocator targeting higher occupancy and parking the ~108-reg sort array
// in AGPRs (VGPR_Count 64-80, ~2.3x VALU-instr inflation from accvgpr
// shuttles + hazard nops). Measured occupancy was already ~2 waves/EU, so
// this gives up nothing and frees the whole array into arch VGPRs.
__global__
__attribute__((amdgpu_flat_work_group_size(256, 256), amdgpu_waves_per_eu(2, 2)))
void wos_kernel(
    const float* __restrict__ x, const float* __restrict__ weight,
    const float* __restrict__ bias, const float* __restrict__ mask,
    float* __restrict__ out)
{
    const int lane = threadIdx.x & 63;
    const int wave = threadIdx.x >> 6;
    const int grp  = blockIdx.x >> 1;
    // nc is wave-uniform: assert it so weight/mask/bias reads become scalar loads.
    const int nc   = __builtin_amdgcn_readfirstlane(((blockIdx.x & 1) << 2) | wave);
    const int n    = grp * 64 + lane;
    if (n >= Ntot) return;

    const int b  = n / Lc;
    const int l  = n - b * Lc;
    const int ho = l / Woc;
    const int wo = l - ho * Woc;

    const float* xb = x + (b * Cc) * (Hc * Wc);
    const float* mk = mask + nc * MDd;      // wave-uniform -> scalar loads
    const float* wr = weight + nc * MDd;    // wave-uniform -> scalar loads
    const float  bi = bias[nc];

    // 64-bit sortable items: high word = exact 32-bit descending-order key of
    // mx (bit-faithful fp32 comparator), low word = element's weight bits
    // (payload; also tie-break — exact fp32 ties are measure-zero).
    unsigned long long it[MDd];
    #pragma unroll
    for (int c = 0; c < 3; ++c) {
        #pragma unroll
        for (int r = 0; r < 3; ++r) {
            #pragma unroll
            for (int s = 0; s < 3; ++s) {
                const int d = c * 9 + r * 3 + s;
                const float v = xb[(c * Hc + ho + r) * Wc + wo + s];
                const float m0 =  v + mk[d];
                const float m1 = -v + mk[27 + d];
                it[d] = ((unsigned long long)inv_key(m0) << 32)
                        | __float_as_uint(wr[d]);
                it[27 + d] = ((unsigned long long)inv_key(m1) << 32)
                             | __float_as_uint(wr[27 + d]);
            }
        }
    }

    // Batcher odd-even mergesort for n=64, pruned to wires < 54 (monotone
    // network => virtual +inf pads on wires 54..63 never move down, so every
    // CE with hi >= 54 is a static no-op). ~440 CEs; correctness-proven in
    // rounds 3-4 (absmax 0.0).
    #pragma unroll
    for (int p = 1; p < 64; p <<= 1) {
        #pragma unroll
        for (int k = p; k >= 1; k >>= 1) {
            #pragma unroll
            for (int j = k % p; j + k < 64; j += 2 * k) {
                #pragma unroll
                for (int i = 0; i < k; ++i) {
                    const int lo = i + j;
                    const int hi = i + j + k;
                    if (hi < MDd && (lo / (2 * p) == hi / (2 * p))) {
                        const unsigned long long a = it[lo], c2 = it[hi];
                        const bool sw = a < c2;
                        it[lo] = sw ? a : c2;
                        it[hi] = sw ? c2 : a;
                    }
                }
            }
        }
    }

    // Sequential fp32 cumsum of weights in sorted (descending-mx) order —
    // bit-matches the reference. Track the key of the last rank whose
    // cumulative weight <= bias; default (clip-to-0) is rank 0's key.
    float acc = 0.0f;
    unsigned sel = (unsigned)(it[0] >> 32);
    #pragma unroll
    for (int r = 0; r < MDd; ++r) {
        acc += __uint_as_float((unsigned)it[r]);
        sel = (acc <= bi) ? (unsigned)(it[r] >> 32) : sel;
    }

    // Invert the (involutive) key transform to recover the exact fp32 value.
    out[n * NCH + nc] = __uint_as_float(inv_key_bits(sel));
}

extern "C" void kernel_launch(void* const* d_in, const int* in_sizes, int n_in,
                              void* d_out, int out_size, void* d_ws, size_t ws_size,
                              hipStream_t stream) {
    const float* x      = (const float*)d_in[0];
    const float* weight = (const float*)d_in[1];
    const float* bias   = (const float*)d_in[2];
    const float* mask   = (const float*)d_in[3];
    float* out = (float*)d_out;

    const int ngrp = (Ntot + 63) / 64;      // 1561
    dim3 grid(ngrp * 2);                    // x2 blocks: 8 nc / 4 waves
    wos_kernel<<<grid, 256, 0, stream>>>(x, weight, bias, mask, out);
}

// Round 6
// 131.451 us; speedup vs baseline: 1.0611x; 1.0611x over previous
//
#include <hip/hip_runtime.h>

// Problem constants (fixed by reference setup_inputs)
constexpr int Cc   = 3;
constexpr int Hc   = 160;
constexpr int Wc   = 160;
constexpr int Hoc  = 158;
constexpr int Woc  = 158;
constexpr int Lc   = Hoc * Woc;    // 24964
constexpr int Ntot = 4 * Lc;       // 99856
constexpr int NCH  = 8;
constexpr int MDd  = 54;           // 2 * C * 3 * 3

// Bijective (involutive) map float-bits <-> uint such that ascending uint
// == DESCENDING float. Applying it twice recovers the original bits.
__device__ __forceinline__ unsigned inv_key_bits(unsigned u) {
    return (u & 0x80000000u) ? u : (~u & 0x7FFFFFFFu);
}
__device__ __forceinline__ unsigned inv_key(float f) {
    return inv_key_bits(__float_as_uint(f));
}

// Rounds 2-5 evidence: the allocator parks the 108-reg sort array in AGPRs
// (VGPR_Count 64-116, occupancy ~2 waves/EU) and pays 8 v_accvgpr_read/write
// shuttles per compare-exchange — measured 6,500 VALU instr/wave vs ~2,900
// in source (450 CEs x 8 = 3,600, exactly the gap). AGPR spilling is a
// regalloc POLICY, not a budget problem: ban it outright. Guarded so an
// older clang degrades to the current passing kernel instead of erroring.
#if __has_attribute(amdgpu_agpr_alloc)
#define NO_AGPR __attribute__((amdgpu_agpr_alloc(0)))
#elif __has_attribute(amdgpu_num_agpr)
#define NO_AGPR __attribute__((amdgpu_num_agpr(0)))
#else
#define NO_AGPR
#endif

// waves_per_eu(2) min-only: guarantee budget 512/2 = 256 regs/wave (demand
// ~160 arch VGPRs with AGPRs banned -> no scratch spill), but let the
// allocator claim 3 waves/EU if pressure allows.
__global__
__attribute__((amdgpu_flat_work_group_size(256, 256), amdgpu_waves_per_eu(2)))
NO_AGPR
void wos_kernel(
    const float* __restrict__ x, const float* __restrict__ weight,
    const float* __restrict__ bias, const float* __restrict__ mask,
    float* __restrict__ out)
{
    const int lane = threadIdx.x & 63;
    const int wave = threadIdx.x >> 6;
    const int grp  = blockIdx.x >> 1;
    // nc is wave-uniform: assert it so weight/mask/bias reads become scalar loads.
    const int nc   = __builtin_amdgcn_readfirstlane(((blockIdx.x & 1) << 2) | wave);
    const int n    = grp * 64 + lane;
    if (n >= Ntot) return;

    const int b  = n / Lc;
    const int l  = n - b * Lc;
    const int ho = l / Woc;
    const int wo = l - ho * Woc;

    const float* xb = x + (b * Cc) * (Hc * Wc);
    const float* mk = mask + nc * MDd;      // wave-uniform -> scalar loads
    const float* wr = weight + nc * MDd;    // wave-uniform -> scalar loads
    const float  bi = bias[nc];

    // 64-bit sortable items: high word = exact 32-bit descending-order key of
    // mx (bit-faithful fp32 comparator), low word = element's weight bits
    // (payload; also tie-break — exact fp32 ties are measure-zero).
    unsigned long long it[MDd];
    #pragma unroll
    for (int c = 0; c < 3; ++c) {
        #pragma unroll
        for (int r = 0; r < 3; ++r) {
            #pragma unroll
            for (int s = 0; s < 3; ++s) {
                const int d = c * 9 + r * 3 + s;
                const float v = xb[(c * Hc + ho + r) * Wc + wo + s];
                const float m0 =  v + mk[d];
                const float m1 = -v + mk[27 + d];
                it[d] = ((unsigned long long)inv_key(m0) << 32)
                        | __float_as_uint(wr[d]);
                it[27 + d] = ((unsigned long long)inv_key(m1) << 32)
                             | __float_as_uint(wr[27 + d]);
            }
        }
    }

    // Batcher odd-even mergesort for n=64, pruned to wires < 54 (monotone
    // network => virtual +inf pads on wires 54..63 never move down, so every
    // CE with hi >= 54 is a static no-op). ~450 CEs; correctness-proven in
    // rounds 3-5 (absmax 0.0).
    #pragma unroll
    for (int p = 1; p < 64; p <<= 1) {
        #pragma unroll
        for (int k = p; k >= 1; k >>= 1) {
            #pragma unroll
            for (int j = k % p; j + k < 64; j += 2 * k) {
                #pragma unroll
                for (int i = 0; i < k; ++i) {
                    const int lo = i + j;
                    const int hi = i + j + k;
                    if (hi < MDd && (lo / (2 * p) == hi / (2 * p))) {
                        const unsigned long long a = it[lo], c2 = it[hi];
                        const bool sw = a < c2;
                        it[lo] = sw ? a : c2;
                        it[hi] = sw ? c2 : a;
                    }
                }
            }
        }
    }

    // Sequential fp32 cumsum of weights in sorted (descending-mx) order —
    // bit-matches the reference. Track the key of the last rank whose
    // cumulative weight <= bias; default (clip-to-0) is rank 0's key.
    float acc = 0.0f;
    unsigned sel = (unsigned)(it[0] >> 32);
    #pragma unroll
    for (int r = 0; r < MDd; ++r) {
        acc += __uint_as_float((unsigned)it[r]);
        sel = (acc <= bi) ? (unsigned)(it[r] >> 32) : sel;
    }

    // Invert the (involutive) key transform to recover the exact fp32 value.
    out[n * NCH + nc] = __uint_as_float(inv_key_bits(sel));
}

extern "C" void kernel_launch(void* const* d_in, const int* in_sizes, int n_in,
                              void* d_out, int out_size, void* d_ws, size_t ws_size,
                              hipStream_t stream) {
    const float* x      = (const float*)d_in[0];
    const float* weight = (const float*)d_in[1];
    const float* bias   = (const float*)d_in[2];
    const float* mask   = (const float*)d_in[3];
    float* out = (float*)d_out;

    const int ngrp = (Ntot + 63) / 64;      // 1561
    dim3 grid(ngrp * 2);                    // x2 blocks: 8 nc / 4 waves
    wos_kernel<<<grid, 256, 0, stream>>>(x, weight, bias, mask, out);
}